// Round 12
// baseline (383.390 us; speedup 1.0000x reference)
//
#include <hip/hip_runtime.h>

typedef short bf16x8 __attribute__((ext_vector_type(8)));
typedef float f32x4 __attribute__((ext_vector_type(4)));

#define NRES 262144
#define BM 32
#define GOODMAGIC 0x600DF00Du

// ws layout: u32 flag @ byte 0 (16B slot), then weights (u16 units, rel. to wt = ws_u16 + 8):
//   WT0H [128c][384k] @ 0      WT0L @ 49152
//   WT1H [128c][128k] @ 98304  WT1L @ 114688
//   WT2H [ 64c][128k] @ 131072 WT2L @ 139264   (cols 50..63 zero)
#define WT0H 0
#define WT0L 49152
#define WT1H 98304
#define WT1L 114688
#define WT2H 131072
#define WT2L 139264
#define PREP_N 73728
#define WS_NEED ((size_t)(16 + PREP_N * 2 * 2))   // 294,928 B

// lddt_ws LDS (u16 units), K-halved A0: 21504 u16 = 43,008 B -> 3 blocks/CU
//   A0H [32][200] @ 0       A0L @ 6400      (LN'd x half-K, bf16 hi/lo)
//   AC0H [32][136] @ 12800  AC0L @ 17152    (act0 hi/lo)
//   A1H @ 0, A1L @ 4352     (act1 hi/lo, alias A0 -- dead after GEMM0)
#define A0Hn 0
#define A0Ln 6400
#define AC0Hn 12800
#define AC0Ln 17152
#define A1Hn 0
#define A1Ln 4352
#define SMU2 21504
#define A0_STR2 200
#define ACT_STR 136

// fallback (R7) LDS map
#define A0H 0
#define A0L 12544
#define AC0H 25088
#define AC0L 29440
#define A1H 0
#define A1L 12544
#define SMU 33792
#define A0_STR 392

__device__ __forceinline__ unsigned short f2bf(float f) {
    unsigned u = __builtin_bit_cast(unsigned, f);
    u += 0x7FFFu + ((u >> 16) & 1u);          // round-to-nearest-even
    return (unsigned short)(u >> 16);
}
__device__ __forceinline__ float bf2f(unsigned short h) {
    unsigned u = ((unsigned)h) << 16;
    return __builtin_bit_cast(float, u);
}

// ---------------- ws path: flag init, prep, full bit-exact check ----------------
__global__ void set_flag(unsigned* flag, unsigned v) {
    if (threadIdx.x == 0 && blockIdx.x == 0) *flag = v;
}

__device__ __forceinline__ void prep_index(int i, const float* w0, const float* w1,
                                           const float* w2, float& v, int& hi_off, int& lo_off) {
    if (i < 49152) {                        // WT0[col][k] = w0[k][col]
        int col = i / 384, k = i % 384;
        v = w0[k * 128 + col]; hi_off = WT0H + i; lo_off = WT0L + i;
    } else if (i < 65536) {                 // WT1[col][k] = w1[k][col]
        int j = i - 49152; int col = j / 128, k = j % 128;
        v = w1[k * 128 + col]; hi_off = WT1H + j; lo_off = WT1L + j;
    } else {                                // WT2[col][k] = w2[k][col], pad col>=50
        int j = i - 65536; int col = j / 128, k = j % 128;
        v = (col < 50) ? w2[k * 50 + col] : 0.0f; hi_off = WT2H + j; lo_off = WT2L + j;
    }
}

__global__ void prep_weights(const float* __restrict__ w0, const float* __restrict__ w1,
                             const float* __restrict__ w2, unsigned short* __restrict__ wt) {
    const int i = blockIdx.x * blockDim.x + threadIdx.x;
    if (i >= PREP_N) return;
    float v; int hi_off, lo_off;
    prep_index(i, w0, w1, w2, v, hi_off, lo_off);
    const unsigned short h = f2bf(v);
    wt[hi_off] = h;
    wt[lo_off] = f2bf(v - bf2f(h));
}

__global__ void check_weights(const float* __restrict__ w0, const float* __restrict__ w1,
                              const float* __restrict__ w2, const unsigned short* __restrict__ wt,
                              unsigned* flag) {
    const int i = blockIdx.x * blockDim.x + threadIdx.x;
    if (i >= PREP_N) return;
    float v; int hi_off, lo_off;
    prep_index(i, w0, w1, w2, v, hi_off, lo_off);
    const unsigned short h = f2bf(v);
    const unsigned short l = f2bf(v - bf2f(h));
    if (wt[hi_off] != h || wt[lo_off] != l) atomicExch(flag, 0xBAD0BAD0u);
}

// ---------------- fast kernel: pre-split weights, K-halved A0, 3 blocks/CU ----------------
__global__ __launch_bounds__(256, 3)
void lddt_ws(const float* __restrict__ x,
             const float* __restrict__ ln_scale,
             const float* __restrict__ ln_bias,
             const unsigned short* __restrict__ wt,
             const unsigned* __restrict__ flag,
             const float* __restrict__ b0,
             const float* __restrict__ b1,
             const float* __restrict__ b2,
             float* __restrict__ out) {
    if (*flag != GOODMAGIC) return;           // uniform early exit -> fallback kernel runs

    __shared__ __align__(16) unsigned short sm[SMU2];
    const int tid  = threadIdx.x;
    const int lane = tid & 63;
    const int l15  = lane & 15;
    const int lg   = lane >> 4;
    const int wid  = tid >> 6;
    const long rowBase = (long)blockIdx.x * BM;

    // ---------------- LayerNorm: half0 (k<192) -> LDS, half1 pre-packed in regs ----------------
    uint2 h1s[2][3], l1s[2][3];               // [rep][cs-3], statically indexed
    {
        const float4* x4 = (const float4*)x;
        const int j = tid & 15;
#pragma unroll
        for (int rep = 0; rep < 2; ++rep) {
            const int row = rep * 16 + (tid >> 4);    // 16 threads per row
            const long gr = rowBase + row;
            float4 v[6];
#pragma unroll
            for (int cs = 0; cs < 6; ++cs)
                v[cs] = x4[gr * 96 + cs * 16 + j];

            float s = 0.f, sq = 0.f;
#pragma unroll
            for (int cs = 0; cs < 6; ++cs) {
                s  += v[cs].x + v[cs].y + v[cs].z + v[cs].w;
                sq += v[cs].x*v[cs].x + v[cs].y*v[cs].y + v[cs].z*v[cs].z + v[cs].w*v[cs].w;
            }
#pragma unroll
            for (int d = 1; d < 16; d <<= 1) {
                s  += __shfl_xor(s,  d);
                sq += __shfl_xor(sq, d);
            }
            const float mu  = s * (1.0f / 384.0f);
            const float var = sq * (1.0f / 384.0f) - mu * mu;
            const float rs  = rsqrtf(var + 1e-5f);
#pragma unroll
            for (int cs = 0; cs < 6; ++cs) {
                const float4 sc = ((const float4*)ln_scale)[cs * 16 + j];
                const float4 bi = ((const float4*)ln_bias )[cs * 16 + j];
                float f[4];
                f[0] = (v[cs].x - mu) * rs * sc.x + bi.x;
                f[1] = (v[cs].y - mu) * rs * sc.y + bi.y;
                f[2] = (v[cs].z - mu) * rs * sc.z + bi.z;
                f[3] = (v[cs].w - mu) * rs * sc.w + bi.w;
                union { unsigned short h[4]; uint2 u; } ph, pl;
#pragma unroll
                for (int e = 0; e < 4; ++e) {
                    ph.h[e] = f2bf(f[e]);
                    pl.h[e] = f2bf(f[e] - bf2f(ph.h[e]));
                }
                if (cs < 3) {
                    const int idx = row * A0_STR2 + cs * 64 + j * 4;
                    *(uint2*)&sm[A0Hn + idx] = ph.u;
                    *(uint2*)&sm[A0Ln + idx] = pl.u;
                } else {
                    h1s[rep][cs - 3] = ph.u;
                    l1s[rep][cs - 3] = pl.u;
                }
            }
        }
    }
    __syncthreads();

    // ---------------- GEMM0: K halves through half-sized A0 ----------------
    {
        f32x4 acc[2][2];
#pragma unroll
        for (int m = 0; m < 2; ++m) { acc[m][0] = (f32x4)0.0f; acc[m][1] = (f32x4)0.0f; }

#define G0SLAB(S, SL)                                                        \
        {                                                                    \
            bf16x8 bh[2], bl[2], ah[2], al[2];                               \
            _Pragma("unroll")                                                \
            for (int n = 0; n < 2; ++n) {                                    \
                const int bcol = wid * 32 + n * 16 + l15;                    \
                bh[n] = *(const bf16x8*)&wt[WT0H + bcol * 384 + (S) * 32 + lg * 8]; \
                bl[n] = *(const bf16x8*)&wt[WT0L + bcol * 384 + (S) * 32 + lg * 8]; \
            }                                                                \
            _Pragma("unroll")                                                \
            for (int m = 0; m < 2; ++m) {                                    \
                const int idx = (m * 16 + l15) * A0_STR2 + (SL) * 32 + lg * 8; \
                ah[m] = *(const bf16x8*)&sm[A0Hn + idx];                     \
                al[m] = *(const bf16x8*)&sm[A0Ln + idx];                     \
            }                                                                \
            _Pragma("unroll")                                                \
            for (int m = 0; m < 2; ++m)                                      \
                _Pragma("unroll")                                            \
                for (int n = 0; n < 2; ++n) {                                \
                    acc[m][n] = __builtin_amdgcn_mfma_f32_16x16x32_bf16(ah[m], bh[n], acc[m][n], 0, 0, 0); \
                    acc[m][n] = __builtin_amdgcn_mfma_f32_16x16x32_bf16(ah[m], bl[n], acc[m][n], 0, 0, 0); \
                    acc[m][n] = __builtin_amdgcn_mfma_f32_16x16x32_bf16(al[m], bh[n], acc[m][n], 0, 0, 0); \
                }                                                            \
        }

#pragma unroll
        for (int s = 0; s < 6; ++s) G0SLAB(s, s)
        __syncthreads();                       // A0 half0 reads complete
        {                                      // dump pre-packed half1
            const int j = tid & 15;
#pragma unroll
            for (int rep = 0; rep < 2; ++rep) {
                const int row = rep * 16 + (tid >> 4);
#pragma unroll
                for (int c = 0; c < 3; ++c) {
                    const int idx = row * A0_STR2 + c * 64 + j * 4;
                    *(uint2*)&sm[A0Hn + idx] = h1s[rep][c];
                    *(uint2*)&sm[A0Ln + idx] = l1s[rep][c];
                }
            }
        }
        __syncthreads();                       // half1 visible
#pragma unroll
        for (int s = 6; s < 12; ++s) G0SLAB(s, s - 6)

#pragma unroll
        for (int m = 0; m < 2; ++m)
#pragma unroll
            for (int n = 0; n < 2; ++n) {
                const int col = wid * 32 + n * 16 + l15;
                const float bb = b0[col];
#pragma unroll
                for (int r = 0; r < 4; ++r) {
                    const int row = m * 16 + lg * 4 + r;
                    const float z = fmaxf(acc[m][n][r] + bb, 0.0f);
                    const unsigned short h = f2bf(z);
                    const int idx = row * ACT_STR + col;
                    sm[AC0Hn + idx] = h;
                    sm[AC0Ln + idx] = f2bf(z - bf2f(h));
                }
            }
    }
    __syncthreads();

    // ---------------- GEMM1: [32,128] @ w1 + b1, ReLU -> act1 (alias A0) ----------------
    {
        f32x4 acc[2][2];
#pragma unroll
        for (int m = 0; m < 2; ++m) { acc[m][0] = (f32x4)0.0f; acc[m][1] = (f32x4)0.0f; }
#pragma unroll
        for (int s = 0; s < 4; ++s) {
            bf16x8 bh[2], bl[2], ah[2], al[2];
#pragma unroll
            for (int n = 0; n < 2; ++n) {
                const int bcol = wid * 32 + n * 16 + l15;
                bh[n] = *(const bf16x8*)&wt[WT1H + bcol * 128 + s * 32 + lg * 8];
                bl[n] = *(const bf16x8*)&wt[WT1L + bcol * 128 + s * 32 + lg * 8];
            }
#pragma unroll
            for (int m = 0; m < 2; ++m) {
                const int idx = (m * 16 + l15) * ACT_STR + s * 32 + lg * 8;
                ah[m] = *(const bf16x8*)&sm[AC0Hn + idx];
                al[m] = *(const bf16x8*)&sm[AC0Ln + idx];
            }
#pragma unroll
            for (int m = 0; m < 2; ++m)
#pragma unroll
                for (int n = 0; n < 2; ++n) {
                    acc[m][n] = __builtin_amdgcn_mfma_f32_16x16x32_bf16(ah[m], bh[n], acc[m][n], 0, 0, 0);
                    acc[m][n] = __builtin_amdgcn_mfma_f32_16x16x32_bf16(ah[m], bl[n], acc[m][n], 0, 0, 0);
                    acc[m][n] = __builtin_amdgcn_mfma_f32_16x16x32_bf16(al[m], bh[n], acc[m][n], 0, 0, 0);
                }
        }
#pragma unroll
        for (int m = 0; m < 2; ++m)
#pragma unroll
            for (int n = 0; n < 2; ++n) {
                const int col = wid * 32 + n * 16 + l15;
                const float bb = b1[col];
#pragma unroll
                for (int r = 0; r < 4; ++r) {
                    const int row = m * 16 + lg * 4 + r;
                    const float z = fmaxf(acc[m][n][r] + bb, 0.0f);
                    const unsigned short h = f2bf(z);
                    const int idx = row * ACT_STR + col;
                    sm[A1Hn + idx] = h;
                    sm[A1Ln + idx] = f2bf(z - bf2f(h));
                }
            }
    }
    __syncthreads();

    // ---------------- GEMM2: [32,128] @ w2[128,50->64] + b2 -> out ----------------
    {
        f32x4 acc[2];
        acc[0] = (f32x4)0.0f; acc[1] = (f32x4)0.0f;
        const int bcol = wid * 16 + l15;
#pragma unroll
        for (int s = 0; s < 4; ++s) {
            bf16x8 bh, bl, ah[2], al[2];
            bh = *(const bf16x8*)&wt[WT2H + bcol * 128 + s * 32 + lg * 8];
            bl = *(const bf16x8*)&wt[WT2L + bcol * 128 + s * 32 + lg * 8];
#pragma unroll
            for (int m = 0; m < 2; ++m) {
                const int idx = (m * 16 + l15) * ACT_STR + s * 32 + lg * 8;
                ah[m] = *(const bf16x8*)&sm[A1Hn + idx];
                al[m] = *(const bf16x8*)&sm[A1Ln + idx];
            }
#pragma unroll
            for (int m = 0; m < 2; ++m) {
                acc[m] = __builtin_amdgcn_mfma_f32_16x16x32_bf16(ah[m], bh, acc[m], 0, 0, 0);
                acc[m] = __builtin_amdgcn_mfma_f32_16x16x32_bf16(ah[m], bl, acc[m], 0, 0, 0);
                acc[m] = __builtin_amdgcn_mfma_f32_16x16x32_bf16(al[m], bh, acc[m], 0, 0, 0);
            }
        }
        if (bcol < 50) {
            const float bb = b2[bcol];
#pragma unroll
            for (int m = 0; m < 2; ++m)
#pragma unroll
                for (int r = 0; r < 4; ++r) {
                    const long row = rowBase + m * 16 + lg * 4 + r;
                    out[row * 50 + bcol] = acc[m][r] + bb;
                }
        }
    }
}

// ---------------- fallback kernel: R7 verbatim (in-kernel weight conversion) ----------------
__device__ __forceinline__ void ln_phase(const float* __restrict__ x,
                                         const float* __restrict__ ln_scale,
                                         const float* __restrict__ ln_bias,
                                         unsigned short* sm, int tid, long rowBase) {
    const float4* x4 = (const float4*)x;
    const int j = tid & 15;
#pragma unroll
    for (int rep = 0; rep < 2; ++rep) {
        const int row = rep * 16 + (tid >> 4);
        const long gr = rowBase + row;
        float4 v[6];
#pragma unroll
        for (int cs = 0; cs < 6; ++cs)
            v[cs] = x4[gr * 96 + cs * 16 + j];

        float s = 0.f, sq = 0.f;
#pragma unroll
        for (int cs = 0; cs < 6; ++cs) {
            s  += v[cs].x + v[cs].y + v[cs].z + v[cs].w;
            sq += v[cs].x*v[cs].x + v[cs].y*v[cs].y + v[cs].z*v[cs].z + v[cs].w*v[cs].w;
        }
#pragma unroll
        for (int d = 1; d < 16; d <<= 1) {
            s  += __shfl_xor(s,  d);
            sq += __shfl_xor(sq, d);
        }
        const float mu  = s * (1.0f / 384.0f);
        const float var = sq * (1.0f / 384.0f) - mu * mu;
        const float rs  = rsqrtf(var + 1e-5f);
#pragma unroll
        for (int cs = 0; cs < 6; ++cs) {
            const float4 sc = ((const float4*)ln_scale)[cs * 16 + j];
            const float4 bi = ((const float4*)ln_bias )[cs * 16 + j];
            float f[4];
            f[0] = (v[cs].x - mu) * rs * sc.x + bi.x;
            f[1] = (v[cs].y - mu) * rs * sc.y + bi.y;
            f[2] = (v[cs].z - mu) * rs * sc.z + bi.z;
            f[3] = (v[cs].w - mu) * rs * sc.w + bi.w;
            union { unsigned short h[4]; uint2 u; } ph, pl;
#pragma unroll
            for (int e = 0; e < 4; ++e) {
                ph.h[e] = f2bf(f[e]);
                pl.h[e] = f2bf(f[e] - bf2f(ph.h[e]));
            }
            const int idx = row * A0_STR + cs * 64 + j * 4;
            *(uint2*)&sm[A0H + idx] = ph.u;
            *(uint2*)&sm[A0L + idx] = pl.u;
        }
    }
}

__device__ __forceinline__ void bfrag(const float* __restrict__ w, int ldw, int col, int k0,
                                      bf16x8& bh, bf16x8& bl) {
    union { unsigned u[4]; bf16x8 v; } H, L;
#pragma unroll
    for (int jj = 0; jj < 4; ++jj) {
        const float f0 = w[(k0 + 2 * jj)     * ldw + col];
        const float f1 = w[(k0 + 2 * jj + 1) * ldw + col];
        const unsigned short h0 = f2bf(f0), h1 = f2bf(f1);
        const unsigned short l0 = f2bf(f0 - bf2f(h0)), l1 = f2bf(f1 - bf2f(h1));
        H.u[jj] = (unsigned)h0 | ((unsigned)h1 << 16);
        L.u[jj] = (unsigned)l0 | ((unsigned)l1 << 16);
    }
    bh = H.v; bl = L.v;
}
__device__ __forceinline__ void bfrag50(const float* __restrict__ w, int col, int k0,
                                        bf16x8& bh, bf16x8& bl) {
    union { unsigned u[4]; bf16x8 v; } H, L;
    const bool ok = (col < 50);
#pragma unroll
    for (int jj = 0; jj < 4; ++jj) {
        const float f0 = ok ? w[(k0 + 2 * jj)     * 50 + col] : 0.0f;
        const float f1 = ok ? w[(k0 + 2 * jj + 1) * 50 + col] : 0.0f;
        const unsigned short h0 = f2bf(f0), h1 = f2bf(f1);
        const unsigned short l0 = f2bf(f0 - bf2f(h0)), l1 = f2bf(f1 - bf2f(h1));
        H.u[jj] = (unsigned)h0 | ((unsigned)h1 << 16);
        L.u[jj] = (unsigned)l0 | ((unsigned)l1 << 16);
    }
    bh = H.v; bl = L.v;
}

__global__ __launch_bounds__(256, 2)
void lddt_conv(const float* __restrict__ x,
               const float* __restrict__ ln_scale,
               const float* __restrict__ ln_bias,
               const float* __restrict__ w0,
               const float* __restrict__ b0,
               const float* __restrict__ w1,
               const float* __restrict__ b1,
               const float* __restrict__ w2,
               const float* __restrict__ b2,
               const unsigned* flag,
               float* __restrict__ out) {
    if (flag && *flag == GOODMAGIC) return;   // ws path handled output

    __shared__ __align__(16) unsigned short sm[SMU];
    const int tid  = threadIdx.x;
    const int lane = tid & 63;
    const int l15  = lane & 15;
    const int lg   = lane >> 4;
    const int wid  = tid >> 6;
    const long rowBase = (long)blockIdx.x * BM;

    ln_phase(x, ln_scale, ln_bias, sm, tid, rowBase);
    __syncthreads();

    {
        f32x4 acc[2][2];
#pragma unroll
        for (int m = 0; m < 2; ++m) { acc[m][0] = (f32x4)0.0f; acc[m][1] = (f32x4)0.0f; }
#pragma unroll
        for (int s = 0; s < 12; ++s) {
            bf16x8 bh[2], bl[2], ah[2], al[2];
#pragma unroll
            for (int n = 0; n < 2; ++n)
                bfrag(w0, 128, wid * 32 + n * 16 + l15, s * 32 + lg * 8, bh[n], bl[n]);
#pragma unroll
            for (int m = 0; m < 2; ++m) {
                const int idx = (m * 16 + l15) * A0_STR + s * 32 + lg * 8;
                ah[m] = *(const bf16x8*)&sm[A0H + idx];
                al[m] = *(const bf16x8*)&sm[A0L + idx];
            }
#pragma unroll
            for (int m = 0; m < 2; ++m)
#pragma unroll
                for (int n = 0; n < 2; ++n) {
                    acc[m][n] = __builtin_amdgcn_mfma_f32_16x16x32_bf16(ah[m], bh[n], acc[m][n], 0, 0, 0);
                    acc[m][n] = __builtin_amdgcn_mfma_f32_16x16x32_bf16(ah[m], bl[n], acc[m][n], 0, 0, 0);
                    acc[m][n] = __builtin_amdgcn_mfma_f32_16x16x32_bf16(al[m], bh[n], acc[m][n], 0, 0, 0);
                }
        }
#pragma unroll
        for (int m = 0; m < 2; ++m)
#pragma unroll
            for (int n = 0; n < 2; ++n) {
                const int col = wid * 32 + n * 16 + l15;
                const float bb = b0[col];
#pragma unroll
                for (int r = 0; r < 4; ++r) {
                    const int row = m * 16 + lg * 4 + r;
                    const float z = fmaxf(acc[m][n][r] + bb, 0.0f);
                    const unsigned short h = f2bf(z);
                    const int idx = row * ACT_STR + col;
                    sm[AC0H + idx] = h;
                    sm[AC0L + idx] = f2bf(z - bf2f(h));
                }
            }
    }
    __syncthreads();

    {
        f32x4 acc[2][2];
#pragma unroll
        for (int m = 0; m < 2; ++m) { acc[m][0] = (f32x4)0.0f; acc[m][1] = (f32x4)0.0f; }
#pragma unroll
        for (int s = 0; s < 4; ++s) {
            bf16x8 bh[2], bl[2], ah[2], al[2];
#pragma unroll
            for (int n = 0; n < 2; ++n)
                bfrag(w1, 128, wid * 32 + n * 16 + l15, s * 32 + lg * 8, bh[n], bl[n]);
#pragma unroll
            for (int m = 0; m < 2; ++m) {
                const int idx = (m * 16 + l15) * ACT_STR + s * 32 + lg * 8;
                ah[m] = *(const bf16x8*)&sm[AC0H + idx];
                al[m] = *(const bf16x8*)&sm[AC0L + idx];
            }
#pragma unroll
            for (int m = 0; m < 2; ++m)
#pragma unroll
                for (int n = 0; n < 2; ++n) {
                    acc[m][n] = __builtin_amdgcn_mfma_f32_16x16x32_bf16(ah[m], bh[n], acc[m][n], 0, 0, 0);
                    acc[m][n] = __builtin_amdgcn_mfma_f32_16x16x32_bf16(ah[m], bl[n], acc[m][n], 0, 0, 0);
                    acc[m][n] = __builtin_amdgcn_mfma_f32_16x16x32_bf16(al[m], bh[n], acc[m][n], 0, 0, 0);
                }
        }
#pragma unroll
        for (int m = 0; m < 2; ++m)
#pragma unroll
            for (int n = 0; n < 2; ++n) {
                const int col = wid * 32 + n * 16 + l15;
                const float bb = b1[col];
#pragma unroll
                for (int r = 0; r < 4; ++r) {
                    const int row = m * 16 + lg * 4 + r;
                    const float z = fmaxf(acc[m][n][r] + bb, 0.0f);
                    const unsigned short h = f2bf(z);
                    const int idx = row * ACT_STR + col;
                    sm[A1H + idx] = h;
                    sm[A1L + idx] = f2bf(z - bf2f(h));
                }
            }
    }
    __syncthreads();

    {
        f32x4 acc[2];
        acc[0] = (f32x4)0.0f; acc[1] = (f32x4)0.0f;
        const int bcol = wid * 16 + l15;
#pragma unroll
        for (int s = 0; s < 4; ++s) {
            bf16x8 bh, bl, ah[2], al[2];
            bfrag50(w2, bcol, s * 32 + lg * 8, bh, bl);
#pragma unroll
            for (int m = 0; m < 2; ++m) {
                const int idx = (m * 16 + l15) * ACT_STR + s * 32 + lg * 8;
                ah[m] = *(const bf16x8*)&sm[A1H + idx];
                al[m] = *(const bf16x8*)&sm[A1L + idx];
            }
#pragma unroll
            for (int m = 0; m < 2; ++m) {
                acc[m] = __builtin_amdgcn_mfma_f32_16x16x32_bf16(ah[m], bh, acc[m], 0, 0, 0);
                acc[m] = __builtin_amdgcn_mfma_f32_16x16x32_bf16(ah[m], bl, acc[m], 0, 0, 0);
                acc[m] = __builtin_amdgcn_mfma_f32_16x16x32_bf16(al[m], bh, acc[m], 0, 0, 0);
            }
        }
        if (bcol < 50) {
            const float bb = b2[bcol];
#pragma unroll
            for (int m = 0; m < 2; ++m)
#pragma unroll
                for (int r = 0; r < 4; ++r) {
                    const long row = rowBase + m * 16 + lg * 4 + r;
                    out[row * 50 + bcol] = acc[m][r] + bb;
                }
        }
    }
}

extern "C" void kernel_launch(void* const* d_in, const int* in_sizes, int n_in,
                              void* d_out, int out_size, void* d_ws, size_t ws_size,
                              hipStream_t stream) {
    const float* x        = (const float*)d_in[0];
    const float* ln_scale = (const float*)d_in[1];
    const float* ln_bias  = (const float*)d_in[2];
    const float* w0       = (const float*)d_in[3];
    const float* b0       = (const float*)d_in[4];
    const float* w1       = (const float*)d_in[5];
    const float* b1       = (const float*)d_in[6];
    const float* w2       = (const float*)d_in[7];
    const float* b2       = (const float*)d_in[8];
    float* out = (float*)d_out;

    const bool ws_ok = (ws_size >= WS_NEED);
    if (ws_ok) {
        unsigned* flag = (unsigned*)d_ws;
        unsigned short* wt = (unsigned short*)d_ws + 8;   // 16B flag slot
        set_flag<<<1, 64, 0, stream>>>(flag, GOODMAGIC);
        prep_weights<<<(PREP_N + 255) / 256, 256, 0, stream>>>(w0, w1, w2, wt);
        check_weights<<<(PREP_N + 255) / 256, 256, 0, stream>>>(w0, w1, w2, wt, flag);
        lddt_ws<<<NRES / BM, 256, 0, stream>>>(
            x, ln_scale, ln_bias, wt, flag, b0, b1, b2, out);
        lddt_conv<<<NRES / BM, 256, 0, stream>>>(
            x, ln_scale, ln_bias, w0, b0, w1, b1, w2, b2, flag, out);
    } else {
        lddt_conv<<<NRES / BM, 256, 0, stream>>>(
            x, ln_scale, ln_bias, w0, b0, w1, b1, w2, b2, (const unsigned*)nullptr, out);
    }
}

// Round 15
// 347.505 us; speedup vs baseline: 1.1033x; 1.1033x over previous
//
#include <hip/hip_runtime.h>

typedef short bf16x8 __attribute__((ext_vector_type(8)));
typedef float f32x4 __attribute__((ext_vector_type(4)));

#define NRES 262144
#define BM 32
#define GOODMAGIC 0x600DF00Du

// ws layout: u32 flag @ byte 0 (16B slot), then weights (u16 units, rel. to wt = ws_u16 + 8):
//   WT0H [128c][384k] @ 0      WT0L @ 49152
//   WT1H [128c][128k] @ 98304  WT1L @ 114688
//   WT2H [ 64c][128k] @ 131072 WT2L @ 139264   (cols 50..63 zero)
#define WT0H 0
#define WT0L 49152
#define WT1H 98304
#define WT1L 114688
#define WT2H 131072
#define WT2L 139264
#define PREP_N 73728
#define WS_NEED ((size_t)(16 + PREP_N * 2 * 2))   // 294,928 B

// LDS (u16 units), padded strides (R4/R7-proven), 67,584 B -> 2 blocks/CU
#define A0H 0
#define A0L 12544
#define AC0H 25088
#define AC0L 29440
#define A1H 0
#define A1L 12544
#define SMU 33792
#define A0_STR 392
#define ACT_STR 136

__device__ __forceinline__ unsigned short f2bf(float f) {
    unsigned u = __builtin_bit_cast(unsigned, f);
    u += 0x7FFFu + ((u >> 16) & 1u);          // round-to-nearest-even
    return (unsigned short)(u >> 16);
}
__device__ __forceinline__ float bf2f(unsigned short h) {
    unsigned u = ((unsigned)h) << 16;
    return __builtin_bit_cast(float, u);
}

// ---------------- ws path: flag init, prep, full bit-exact check ----------------
__global__ void set_flag(unsigned* flag, unsigned v) {
    if (threadIdx.x == 0 && blockIdx.x == 0) *flag = v;
}

__device__ __forceinline__ void prep_index(int i, const float* w0, const float* w1,
                                           const float* w2, float& v, int& hi_off, int& lo_off) {
    if (i < 49152) {                        // WT0[col][k] = w0[k][col]
        int col = i / 384, k = i % 384;
        v = w0[k * 128 + col]; hi_off = WT0H + i; lo_off = WT0L + i;
    } else if (i < 65536) {                 // WT1[col][k] = w1[k][col]
        int j = i - 49152; int col = j / 128, k = j % 128;
        v = w1[k * 128 + col]; hi_off = WT1H + j; lo_off = WT1L + j;
    } else {                                // WT2[col][k] = w2[k][col], pad col>=50
        int j = i - 65536; int col = j / 128, k = j % 128;
        v = (col < 50) ? w2[k * 50 + col] : 0.0f; hi_off = WT2H + j; lo_off = WT2L + j;
    }
}

__global__ void prep_weights(const float* __restrict__ w0, const float* __restrict__ w1,
                             const float* __restrict__ w2, unsigned short* __restrict__ wt) {
    const int i = blockIdx.x * blockDim.x + threadIdx.x;
    if (i >= PREP_N) return;
    float v; int hi_off, lo_off;
    prep_index(i, w0, w1, w2, v, hi_off, lo_off);
    const unsigned short h = f2bf(v);
    wt[hi_off] = h;
    wt[lo_off] = f2bf(v - bf2f(h));
}

__global__ void check_weights(const float* __restrict__ w0, const float* __restrict__ w1,
                              const float* __restrict__ w2, const unsigned short* __restrict__ wt,
                              unsigned* flag) {
    const int i = blockIdx.x * blockDim.x + threadIdx.x;
    if (i >= PREP_N) return;
    float v; int hi_off, lo_off;
    prep_index(i, w0, w1, w2, v, hi_off, lo_off);
    const unsigned short h = f2bf(v);
    const unsigned short l = f2bf(v - bf2f(h));
    if (wt[hi_off] != h || wt[lo_off] != l) atomicExch(flag, 0xBAD0BAD0u);
}

// ---------------- shared LayerNorm phase (R7 verbatim) ----------------
__device__ __forceinline__ void ln_phase(const float* __restrict__ x,
                                         const float* __restrict__ ln_scale,
                                         const float* __restrict__ ln_bias,
                                         unsigned short* sm, int tid, long rowBase) {
    const float4* x4 = (const float4*)x;
    const int j = tid & 15;
#pragma unroll
    for (int rep = 0; rep < 2; ++rep) {
        const int row = rep * 16 + (tid >> 4);    // 16 threads per row
        const long gr = rowBase + row;
        float4 v[6];
#pragma unroll
        for (int cs = 0; cs < 6; ++cs)
            v[cs] = x4[gr * 96 + cs * 16 + j];

        float s = 0.f, sq = 0.f;
#pragma unroll
        for (int cs = 0; cs < 6; ++cs) {
            s  += v[cs].x + v[cs].y + v[cs].z + v[cs].w;
            sq += v[cs].x*v[cs].x + v[cs].y*v[cs].y + v[cs].z*v[cs].z + v[cs].w*v[cs].w;
        }
#pragma unroll
        for (int d = 1; d < 16; d <<= 1) {
            s  += __shfl_xor(s,  d);
            sq += __shfl_xor(sq, d);
        }
        const float mu  = s * (1.0f / 384.0f);
        const float var = sq * (1.0f / 384.0f) - mu * mu;
        const float rs  = rsqrtf(var + 1e-5f);
#pragma unroll
        for (int cs = 0; cs < 6; ++cs) {
            const float4 sc = ((const float4*)ln_scale)[cs * 16 + j];
            const float4 bi = ((const float4*)ln_bias )[cs * 16 + j];
            float f[4];
            f[0] = (v[cs].x - mu) * rs * sc.x + bi.x;
            f[1] = (v[cs].y - mu) * rs * sc.y + bi.y;
            f[2] = (v[cs].z - mu) * rs * sc.z + bi.z;
            f[3] = (v[cs].w - mu) * rs * sc.w + bi.w;
            union { unsigned short h[4]; uint2 u; } ph, pl;
#pragma unroll
            for (int e = 0; e < 4; ++e) {
                ph.h[e] = f2bf(f[e]);
                pl.h[e] = f2bf(f[e] - bf2f(ph.h[e]));
            }
            const int idx = row * A0_STR + cs * 64 + j * 4;
            *(uint2*)&sm[A0H + idx] = ph.u;
            *(uint2*)&sm[A0L + idx] = pl.u;
        }
    }
}

// ---------------- fast kernel: weights pre-split in ws ----------------
__global__ __launch_bounds__(256, 2)
void lddt_ws(const float* __restrict__ x,
             const float* __restrict__ ln_scale,
             const float* __restrict__ ln_bias,
             const unsigned short* __restrict__ wt,
             const unsigned* __restrict__ flag,
             const float* __restrict__ b0,
             const float* __restrict__ b1,
             const float* __restrict__ b2,
             float* __restrict__ out) {
    if (*flag != GOODMAGIC) return;           // uniform early exit -> fallback kernel runs

    __shared__ __align__(16) unsigned short sm[SMU];
    const int tid  = threadIdx.x;
    const int lane = tid & 63;
    const int l15  = lane & 15;
    const int lg   = lane >> 4;
    const int wid  = tid >> 6;
    const long rowBase = (long)blockIdx.x * BM;

    ln_phase(x, ln_scale, ln_bias, sm, tid, rowBase);
    __syncthreads();

    // GEMM0
    {
        f32x4 acc[2][2];
#pragma unroll
        for (int m = 0; m < 2; ++m) { acc[m][0] = (f32x4)0.0f; acc[m][1] = (f32x4)0.0f; }
#pragma unroll
        for (int s = 0; s < 12; ++s) {
            bf16x8 bh[2], bl[2], ah[2], al[2];
#pragma unroll
            for (int n = 0; n < 2; ++n) {
                const int bcol = wid * 32 + n * 16 + l15;
                bh[n] = *(const bf16x8*)&wt[WT0H + bcol * 384 + s * 32 + lg * 8];
                bl[n] = *(const bf16x8*)&wt[WT0L + bcol * 384 + s * 32 + lg * 8];
            }
#pragma unroll
            for (int m = 0; m < 2; ++m) {
                const int idx = (m * 16 + l15) * A0_STR + s * 32 + lg * 8;
                ah[m] = *(const bf16x8*)&sm[A0H + idx];
                al[m] = *(const bf16x8*)&sm[A0L + idx];
            }
#pragma unroll
            for (int m = 0; m < 2; ++m)
#pragma unroll
                for (int n = 0; n < 2; ++n) {
                    acc[m][n] = __builtin_amdgcn_mfma_f32_16x16x32_bf16(ah[m], bh[n], acc[m][n], 0, 0, 0);
                    acc[m][n] = __builtin_amdgcn_mfma_f32_16x16x32_bf16(ah[m], bl[n], acc[m][n], 0, 0, 0);
                    acc[m][n] = __builtin_amdgcn_mfma_f32_16x16x32_bf16(al[m], bh[n], acc[m][n], 0, 0, 0);
                }
        }
#pragma unroll
        for (int m = 0; m < 2; ++m)
#pragma unroll
            for (int n = 0; n < 2; ++n) {
                const int col = wid * 32 + n * 16 + l15;
                const float bb = b0[col];
#pragma unroll
                for (int r = 0; r < 4; ++r) {
                    const int row = m * 16 + lg * 4 + r;
                    const float z = fmaxf(acc[m][n][r] + bb, 0.0f);
                    const unsigned short h = f2bf(z);
                    const int idx = row * ACT_STR + col;
                    sm[AC0H + idx] = h;
                    sm[AC0L + idx] = f2bf(z - bf2f(h));
                }
            }
    }
    __syncthreads();

    // GEMM1
    {
        f32x4 acc[2][2];
#pragma unroll
        for (int m = 0; m < 2; ++m) { acc[m][0] = (f32x4)0.0f; acc[m][1] = (f32x4)0.0f; }
#pragma unroll
        for (int s = 0; s < 4; ++s) {
            bf16x8 bh[2], bl[2], ah[2], al[2];
#pragma unroll
            for (int n = 0; n < 2; ++n) {
                const int bcol = wid * 32 + n * 16 + l15;
                bh[n] = *(const bf16x8*)&wt[WT1H + bcol * 128 + s * 32 + lg * 8];
                bl[n] = *(const bf16x8*)&wt[WT1L + bcol * 128 + s * 32 + lg * 8];
            }
#pragma unroll
            for (int m = 0; m < 2; ++m) {
                const int idx = (m * 16 + l15) * ACT_STR + s * 32 + lg * 8;
                ah[m] = *(const bf16x8*)&sm[AC0H + idx];
                al[m] = *(const bf16x8*)&sm[AC0L + idx];
            }
#pragma unroll
            for (int m = 0; m < 2; ++m)
#pragma unroll
                for (int n = 0; n < 2; ++n) {
                    acc[m][n] = __builtin_amdgcn_mfma_f32_16x16x32_bf16(ah[m], bh[n], acc[m][n], 0, 0, 0);
                    acc[m][n] = __builtin_amdgcn_mfma_f32_16x16x32_bf16(ah[m], bl[n], acc[m][n], 0, 0, 0);
                    acc[m][n] = __builtin_amdgcn_mfma_f32_16x16x32_bf16(al[m], bh[n], acc[m][n], 0, 0, 0);
                }
        }
#pragma unroll
        for (int m = 0; m < 2; ++m)
#pragma unroll
            for (int n = 0; n < 2; ++n) {
                const int col = wid * 32 + n * 16 + l15;
                const float bb = b1[col];
#pragma unroll
                for (int r = 0; r < 4; ++r) {
                    const int row = m * 16 + lg * 4 + r;
                    const float z = fmaxf(acc[m][n][r] + bb, 0.0f);
                    const unsigned short h = f2bf(z);
                    const int idx = row * ACT_STR + col;
                    sm[A1H + idx] = h;
                    sm[A1L + idx] = f2bf(z - bf2f(h));
                }
            }
    }
    __syncthreads();

    // GEMM2
    {
        f32x4 acc[2];
        acc[0] = (f32x4)0.0f; acc[1] = (f32x4)0.0f;
        const int bcol = wid * 16 + l15;
#pragma unroll
        for (int s = 0; s < 4; ++s) {
            bf16x8 bh, bl, ah[2], al[2];
            bh = *(const bf16x8*)&wt[WT2H + bcol * 128 + s * 32 + lg * 8];
            bl = *(const bf16x8*)&wt[WT2L + bcol * 128 + s * 32 + lg * 8];
#pragma unroll
            for (int m = 0; m < 2; ++m) {
                const int idx = (m * 16 + l15) * ACT_STR + s * 32 + lg * 8;
                ah[m] = *(const bf16x8*)&sm[A1H + idx];
                al[m] = *(const bf16x8*)&sm[A1L + idx];
            }
#pragma unroll
            for (int m = 0; m < 2; ++m) {
                acc[m] = __builtin_amdgcn_mfma_f32_16x16x32_bf16(ah[m], bh, acc[m], 0, 0, 0);
                acc[m] = __builtin_amdgcn_mfma_f32_16x16x32_bf16(ah[m], bl, acc[m], 0, 0, 0);
                acc[m] = __builtin_amdgcn_mfma_f32_16x16x32_bf16(al[m], bh, acc[m], 0, 0, 0);
            }
        }
        if (bcol < 50) {
            const float bb = b2[bcol];
#pragma unroll
            for (int m = 0; m < 2; ++m)
#pragma unroll
                for (int r = 0; r < 4; ++r) {
                    const long row = rowBase + m * 16 + lg * 4 + r;
                    out[row * 50 + bcol] = acc[m][r] + bb;
                }
        }
    }
}

// ---------------- fallback kernel: R7 verbatim (in-kernel weight conversion) ----------------
__device__ __forceinline__ void bfrag(const float* __restrict__ w, int ldw, int col, int k0,
                                      bf16x8& bh, bf16x8& bl) {
    union { unsigned u[4]; bf16x8 v; } H, L;
#pragma unroll
    for (int jj = 0; jj < 4; ++jj) {
        const float f0 = w[(k0 + 2 * jj)     * ldw + col];
        const float f1 = w[(k0 + 2 * jj + 1) * ldw + col];
        const unsigned short h0 = f2bf(f0), h1 = f2bf(f1);
        const unsigned short l0 = f2bf(f0 - bf2f(h0)), l1 = f2bf(f1 - bf2f(h1));
        H.u[jj] = (unsigned)h0 | ((unsigned)h1 << 16);
        L.u[jj] = (unsigned)l0 | ((unsigned)l1 << 16);
    }
    bh = H.v; bl = L.v;
}
__device__ __forceinline__ void bfrag50(const float* __restrict__ w, int col, int k0,
                                        bf16x8& bh, bf16x8& bl) {
    union { unsigned u[4]; bf16x8 v; } H, L;
    const bool ok = (col < 50);
#pragma unroll
    for (int jj = 0; jj < 4; ++jj) {
        const float f0 = ok ? w[(k0 + 2 * jj)     * 50 + col] : 0.0f;
        const float f1 = ok ? w[(k0 + 2 * jj + 1) * 50 + col] : 0.0f;
        const unsigned short h0 = f2bf(f0), h1 = f2bf(f1);
        const unsigned short l0 = f2bf(f0 - bf2f(h0)), l1 = f2bf(f1 - bf2f(h1));
        H.u[jj] = (unsigned)h0 | ((unsigned)h1 << 16);
        L.u[jj] = (unsigned)l0 | ((unsigned)l1 << 16);
    }
    bh = H.v; bl = L.v;
}

__global__ __launch_bounds__(256, 2)
void lddt_conv(const float* __restrict__ x,
               const float* __restrict__ ln_scale,
               const float* __restrict__ ln_bias,
               const float* __restrict__ w0,
               const float* __restrict__ b0,
               const float* __restrict__ w1,
               const float* __restrict__ b1,
               const float* __restrict__ w2,
               const float* __restrict__ b2,
               const unsigned* flag,
               float* __restrict__ out) {
    if (flag && *flag == GOODMAGIC) return;   // ws path handled output

    __shared__ __align__(16) unsigned short sm[SMU];
    const int tid  = threadIdx.x;
    const int lane = tid & 63;
    const int l15  = lane & 15;
    const int lg   = lane >> 4;
    const int wid  = tid >> 6;
    const long rowBase = (long)blockIdx.x * BM;

    ln_phase(x, ln_scale, ln_bias, sm, tid, rowBase);
    __syncthreads();

    {
        f32x4 acc[2][2];
#pragma unroll
        for (int m = 0; m < 2; ++m) { acc[m][0] = (f32x4)0.0f; acc[m][1] = (f32x4)0.0f; }
#pragma unroll
        for (int s = 0; s < 12; ++s) {
            bf16x8 bh[2], bl[2], ah[2], al[2];
#pragma unroll
            for (int n = 0; n < 2; ++n)
                bfrag(w0, 128, wid * 32 + n * 16 + l15, s * 32 + lg * 8, bh[n], bl[n]);
#pragma unroll
            for (int m = 0; m < 2; ++m) {
                const int idx = (m * 16 + l15) * A0_STR + s * 32 + lg * 8;
                ah[m] = *(const bf16x8*)&sm[A0H + idx];
                al[m] = *(const bf16x8*)&sm[A0L + idx];
            }
#pragma unroll
            for (int m = 0; m < 2; ++m)
#pragma unroll
                for (int n = 0; n < 2; ++n) {
                    acc[m][n] = __builtin_amdgcn_mfma_f32_16x16x32_bf16(ah[m], bh[n], acc[m][n], 0, 0, 0);
                    acc[m][n] = __builtin_amdgcn_mfma_f32_16x16x32_bf16(ah[m], bl[n], acc[m][n], 0, 0, 0);
                    acc[m][n] = __builtin_amdgcn_mfma_f32_16x16x32_bf16(al[m], bh[n], acc[m][n], 0, 0, 0);
                }
        }
#pragma unroll
        for (int m = 0; m < 2; ++m)
#pragma unroll
            for (int n = 0; n < 2; ++n) {
                const int col = wid * 32 + n * 16 + l15;
                const float bb = b0[col];
#pragma unroll
                for (int r = 0; r < 4; ++r) {
                    const int row = m * 16 + lg * 4 + r;
                    const float z = fmaxf(acc[m][n][r] + bb, 0.0f);
                    const unsigned short h = f2bf(z);
                    const int idx = row * ACT_STR + col;
                    sm[AC0H + idx] = h;
                    sm[AC0L + idx] = f2bf(z - bf2f(h));
                }
            }
    }
    __syncthreads();

    {
        f32x4 acc[2][2];
#pragma unroll
        for (int m = 0; m < 2; ++m) { acc[m][0] = (f32x4)0.0f; acc[m][1] = (f32x4)0.0f; }
#pragma unroll
        for (int s = 0; s < 4; ++s) {
            bf16x8 bh[2], bl[2], ah[2], al[2];
#pragma unroll
            for (int n = 0; n < 2; ++n)
                bfrag(w1, 128, wid * 32 + n * 16 + l15, s * 32 + lg * 8, bh[n], bl[n]);
#pragma unroll
            for (int m = 0; m < 2; ++m) {
                const int idx = (m * 16 + l15) * ACT_STR + s * 32 + lg * 8;
                ah[m] = *(const bf16x8*)&sm[AC0H + idx];
                al[m] = *(const bf16x8*)&sm[AC0L + idx];
            }
#pragma unroll
            for (int m = 0; m < 2; ++m)
#pragma unroll
                for (int n = 0; n < 2; ++n) {
                    acc[m][n] = __builtin_amdgcn_mfma_f32_16x16x32_bf16(ah[m], bh[n], acc[m][n], 0, 0, 0);
                    acc[m][n] = __builtin_amdgcn_mfma_f32_16x16x32_bf16(ah[m], bl[n], acc[m][n], 0, 0, 0);
                    acc[m][n] = __builtin_amdgcn_mfma_f32_16x16x32_bf16(al[m], bh[n], acc[m][n], 0, 0, 0);
                }
        }
#pragma unroll
        for (int m = 0; m < 2; ++m)
#pragma unroll
            for (int n = 0; n < 2; ++n) {
                const int col = wid * 32 + n * 16 + l15;
                const float bb = b1[col];
#pragma unroll
                for (int r = 0; r < 4; ++r) {
                    const int row = m * 16 + lg * 4 + r;
                    const float z = fmaxf(acc[m][n][r] + bb, 0.0f);
                    const unsigned short h = f2bf(z);
                    const int idx = row * ACT_STR + col;
                    sm[A1H + idx] = h;
                    sm[A1L + idx] = f2bf(z - bf2f(h));
                }
            }
    }
    __syncthreads();

    {
        f32x4 acc[2];
        acc[0] = (f32x4)0.0f; acc[1] = (f32x4)0.0f;
        const int bcol = wid * 16 + l15;
#pragma unroll
        for (int s = 0; s < 4; ++s) {
            bf16x8 bh, bl, ah[2], al[2];
            bfrag50(w2, bcol, s * 32 + lg * 8, bh, bl);
#pragma unroll
            for (int m = 0; m < 2; ++m) {
                const int idx = (m * 16 + l15) * ACT_STR + s * 32 + lg * 8;
                ah[m] = *(const bf16x8*)&sm[A1H + idx];
                al[m] = *(const bf16x8*)&sm[A1L + idx];
            }
#pragma unroll
            for (int m = 0; m < 2; ++m) {
                acc[m] = __builtin_amdgcn_mfma_f32_16x16x32_bf16(ah[m], bh, acc[m], 0, 0, 0);
                acc[m] = __builtin_amdgcn_mfma_f32_16x16x32_bf16(ah[m], bl, acc[m], 0, 0, 0);
                acc[m] = __builtin_amdgcn_mfma_f32_16x16x32_bf16(al[m], bh, acc[m], 0, 0, 0);
            }
        }
        if (bcol < 50) {
            const float bb = b2[bcol];
#pragma unroll
            for (int m = 0; m < 2; ++m)
#pragma unroll
                for (int r = 0; r < 4; ++r) {
                    const long row = rowBase + m * 16 + lg * 4 + r;
                    out[row * 50 + bcol] = acc[m][r] + bb;
                }
        }
    }
}

extern "C" void kernel_launch(void* const* d_in, const int* in_sizes, int n_in,
                              void* d_out, int out_size, void* d_ws, size_t ws_size,
                              hipStream_t stream) {
    const float* x        = (const float*)d_in[0];
    const float* ln_scale = (const float*)d_in[1];
    const float* ln_bias  = (const float*)d_in[2];
    const float* w0       = (const float*)d_in[3];
    const float* b0       = (const float*)d_in[4];
    const float* w1       = (const float*)d_in[5];
    const float* b1       = (const float*)d_in[6];
    const float* w2       = (const float*)d_in[7];
    const float* b2       = (const float*)d_in[8];
    float* out = (float*)d_out;

    const bool ws_ok = (ws_size >= WS_NEED);
    if (ws_ok) {
        unsigned* flag = (unsigned*)d_ws;
        unsigned short* wt = (unsigned short*)d_ws + 8;   // 16B flag slot
        set_flag<<<1, 64, 0, stream>>>(flag, GOODMAGIC);
        prep_weights<<<(PREP_N + 255) / 256, 256, 0, stream>>>(w0, w1, w2, wt);
        check_weights<<<(PREP_N + 255) / 256, 256, 0, stream>>>(w0, w1, w2, wt, flag);
        lddt_ws<<<NRES / BM, 256, 0, stream>>>(
            x, ln_scale, ln_bias, wt, flag, b0, b1, b2, out);
        lddt_conv<<<NRES / BM, 256, 0, stream>>>(
            x, ln_scale, ln_bias, w0, b0, w1, b1, w2, b2, flag, out);
    } else {
        lddt_conv<<<NRES / BM, 256, 0, stream>>>(
            x, ln_scale, ln_bias, w0, b0, w1, b1, w2, b2, (const unsigned*)nullptr, out);
    }
}